// Round 10
// baseline (7530.531 us; speedup 1.0000x reference)
//
#include <hip/hip_runtime.h>
#include <hip/hip_bf16.h>
#include <stdint.h>

// CTRNN: B=64, T=1000, N_IN=128, N_REC=1024, N_OUT=64
// Persistent-group design, round 12 (XCD-local groups, R4 protocol verbatim):
//   grid = 512 WGs x 256 threads. group g = bid&7 (8 groups x 8 batches),
//   member m = bid>>3 (64 members, each owns 16 neurons and output o=m).
//   WHY: R4's counters show FETCH=163KB/step vs ~8MB/step of poll loads ->
//   98% of agent-scope relaxed loads HIT the per-XCD L2. The exchange
//   latency is therefore the producer store's IC-directory INVALIDATION
//   chasing 8 sharer XCDs (each group's WGs strided across all XCDs),
//   re-amplified as consumers refill lines into 8 L2s every step. With
//   g=bid&7 under the round-robin XCD=bid%8 dispatch, all 64 members of a
//   group share ONE XCD: store->local-L2->load is a ~200-400cy loop with a
//   single-sharer invalidation, no cross-XCD chase.
//   UNLIKE round-3's hang: no fast path, no roster, no hwreg, no sc0.
//   The exchange is bit-identical to twice-verified R4 (agent-scope relaxed
//   atomics); correctness/liveness hold under ANY placement (G16) --
//   placement affects only speed.
//   MFMA keeps 16 batch cols; cols 8-15 duplicate 0-7 (dup threads compute
//   identical values; h/y global stores guarded to the real 8).
//   Protocol (R4 verbatim): tag in bit31 of each packed 32b h word
//   (h=retanh>=0, sign free). Producer tags ((t+1)>>1)&1 and just stores.
//   Consumer: per-chunk retry with per-lane pending mask + s_sleep backoff.
//   Period-4 slot/phase disambiguation; accepted snapshot final; hbuf
//   pre-poisoned 0xFF protects t=0/1.

#define B_    64
#define T_    1000
#define NIN   128
#define NREC  1024
#define NOUT  64
#define GROUPS  8
#define MEMBERS 64
#define BPG   8    // real batches per group (cols 8..15 are duplicates)
#define NSL   16   // n-slice per member

#define DT    0.1f

typedef short  bf16x8 __attribute__((ext_vector_type(8)));
typedef float  f32x4  __attribute__((ext_vector_type(4)));

#define SCOPE __HIP_MEMORY_SCOPE_AGENT

// ws layout
#define XB_OFF     0
#define XB_BYTES   (B_ * T_ * NIN * 2)                      // 16,384,000 (16B aligned)
#define HBUF_OFF   (XB_OFF + XB_BYTES)
#define HBUF_BYTES (GROUPS * 2 * BPG * NREC * 2)            // 262,144

#define TAGMASK 0x8000000080000000ull

union U16B { unsigned long long q[2]; bf16x8 s; };

__device__ __forceinline__ unsigned short f2bf(float f) {
    unsigned u = __float_as_uint(f);
    unsigned r = u + 0x7fffu + ((u >> 16) & 1u);
    return (unsigned short)(r >> 16);
}
__device__ __forceinline__ unsigned pack2(float lo, float hi) {
    return (unsigned)f2bf(lo) | ((unsigned)f2bf(hi) << 16);
}

__global__ void cast_x_kernel(const float* __restrict__ x, unsigned short* __restrict__ xb, int n4) {
    int i = blockIdx.x * blockDim.x + threadIdx.x;
    int stride = gridDim.x * blockDim.x;
    for (; i < n4; i += stride) {
        float4 v = ((const float4*)x)[i];
        unsigned lo = pack2(v.x, v.y);
        unsigned hi = pack2(v.z, v.w);
        ((uint2*)xb)[i] = make_uint2(lo, hi);
    }
}

__global__ __launch_bounds__(256, 1)
void rnn_main(const float* __restrict__ Wahx, const float* __restrict__ Wahh,
              const float* __restrict__ Wyh,  const float* __restrict__ bah,
              const float* __restrict__ by,   const float* __restrict__ ah0,
              const float* __restrict__ mask,
              const unsigned short* __restrict__ xb,
              unsigned short* __restrict__ hbuf,
              float* __restrict__ y)
{
    __shared__ unsigned short weff[NSL * NREC];   // 32 KB, swizzled rows
    __shared__ unsigned short wahxs[NSL * NIN];   // 4 KB, swizzled rows
    __shared__ unsigned short wyhs[NREC];         // 2 KB, single row o=m
    __shared__ float red[4][2][64][4];            // 8 KB: [wave][rec/y][lane][reg]

    const int tid  = threadIdx.x;
    const int w    = tid >> 6;        // wave 0..3 (K-range w*256..)
    const int lane = tid & 63;
    const int bid  = blockIdx.x;
    const int g    = bid & 7;         // group (XCD g under round-robin dispatch)
    const int m    = bid >> 3;        // member 0..63

    // ---- init: build LDS slabs ----
    for (int cc = 0; cc < 8; ++cc) {
        int cid = cc * 256 + tid;           // 2048 chunks of 8
        int rl = cid >> 7;                  // local row 0..15
        int k  = (cid & 127) * 8;
        const float* wr = Wahh + (m * NSL + rl) * NREC + k;
        const float* mr = mask + (m * NSL + rl) * NREC + k;
        float4 a0 = *(const float4*)wr;     float4 a1 = *(const float4*)(wr + 4);
        float4 m0 = *(const float4*)mr;     float4 m1 = *(const float4*)(mr + 4);
        uint4 pk;
        pk.x = pack2(fabsf(a0.x) * m0.x, fabsf(a0.y) * m0.y);
        pk.y = pack2(fabsf(a0.z) * m0.z, fabsf(a0.w) * m0.w);
        pk.z = pack2(fabsf(a1.x) * m1.x, fabsf(a1.y) * m1.y);
        pk.w = pack2(fabsf(a1.z) * m1.z, fabsf(a1.w) * m1.w);
        int byte = (rl * 2048 + k * 2) ^ ((rl & 7) << 4);
        *(uint4*)((char*)weff + byte) = pk;
    }
    {
        int rl = tid >> 4;
        int k  = (tid & 15) * 8;
        const float* wr = Wahx + (m * NSL + rl) * NIN + k;
        float4 a0 = *(const float4*)wr;  float4 a1 = *(const float4*)(wr + 4);
        uint4 pk;
        pk.x = pack2(a0.x, a0.y); pk.y = pack2(a0.z, a0.w);
        pk.z = pack2(a1.x, a1.y); pk.w = pack2(a1.z, a1.w);
        int byte = (rl * 256 + k * 2) ^ ((rl & 7) << 4);
        *(uint4*)((char*)wahxs + byte) = pk;
    }
    if (tid < 128) {
        int k = tid * 8;
        const float* wr = Wyh + m * NREC + k;
        float4 a0 = *(const float4*)wr;  float4 a1 = *(const float4*)(wr + 4);
        uint4 pk;
        pk.x = pack2(a0.x, a0.y); pk.y = pack2(a0.z, a0.w);
        pk.z = pack2(a1.x, a1.y); pk.w = pack2(a1.z, a1.w);
        *(uint4*)((char*)wyhs + k * 2) = pk;
    }

    // per-thread state: (b_loc, nl); b_loc >= 8 are duplicate threads
    const int b_loc = tid >> 4;
    const int nl    = tid & 15;
    const int n_g   = m * NSL + nl;
    float ahv  = ah0[n_g];
    float bahv = bah[n_g];
    float byv  = by[m];

    // h(0) = retanh(ah0) -> hbuf slot 0, tag 0 (natural sign bits)
    {
        float th = tanhf(ahv);
        float h0 = th > 0.f ? th : 0.f;
        unsigned hb = f2bf(h0);
        unsigned nb = __shfl_down(hb, 1);
        if ((nl & 1) == 0 && b_loc < BPG) {
            unsigned w32 = hb | (nb << 16);
            int eidx = ((g * 2 + 0) * BPG + b_loc) * NREC + n_g;
            __hip_atomic_store((unsigned*)hbuf + (eidx >> 1), w32, __ATOMIC_RELAXED, SCOPE);
        }
    }
    __syncthreads();   // LDS slabs ready before use

    const int bcol = lane & 15;          // batch col for MFMA (8-15 dup 0-7)
    const int brow = bcol & (BPG - 1);   // real batch row in hbuf/xb
    const int khi  = (lane >> 4) * 8;    // per-lane k offset within 32-chunk

    for (int t = 0; t <= T_; ++t) {
        // ---- prefetch x fragment (independent of h(t)) ----
        bf16x8 xf, axf;
        if (t < T_) {
            int i = w * 32 + khi;
            xf = *(const bf16x8*)(xb + ((size_t)(g * BPG + brow) * T_ + t) * NIN + i);
            int byte = (bcol * 256 + i * 2) ^ ((bcol & 7) << 4);
            axf = *(const bf16x8*)((const char*)wahxs + byte);
        }

        // ---- poll-load h(t): per-chunk retry, tags self-certify ----
        const int slot = t & 1;
        const unsigned long long want = ((t >> 1) & 1) ? TAGMASK : 0ull;
        const unsigned long long* hq =
            (const unsigned long long*)(hbuf + ((g * 2 + slot) * BPG + brow) * NREC);

        U16B u[8];
        unsigned pend = 0xFFu;           // per-lane pending chunk mask
        for (;;) {
            #pragma unroll
            for (int c = 0; c < 8; ++c) {
                if (pend & (1u << c)) {
                    int k = w * 256 + c * 32 + khi;
                    u[c].q[0] = __hip_atomic_load(hq + (k >> 2),     __ATOMIC_RELAXED, SCOPE);
                    u[c].q[1] = __hip_atomic_load(hq + (k >> 2) + 1, __ATOMIC_RELAXED, SCOPE);
                }
            }
            unsigned np = 0u;
            #pragma unroll
            for (int c = 0; c < 8; ++c) {
                if (pend & (1u << c)) {
                    unsigned long long d = ((u[c].q[0] ^ want) | (u[c].q[1] ^ want)) & TAGMASK;
                    np |= d ? (1u << c) : 0u;
                }
            }
            pend = np;
            if (!__any(pend != 0u)) break;
            __builtin_amdgcn_s_sleep(1);   // ~64cy backoff: don't hammer the LLC
        }
        bf16x8 bfrag[8];
        #pragma unroll
        for (int c = 0; c < 8; ++c) {
            u[c].q[0] &= ~TAGMASK;      // clear tags (real sign bits are 0)
            u[c].q[1] &= ~TAGMASK;
            bfrag[c] = u[c].s;
        }

        f32x4 acc = {0.f, 0.f, 0.f, 0.f};
        if (t < T_) {
            // two independent accumulators halve the serial MFMA dep chain
            f32x4 a0 = {0.f, 0.f, 0.f, 0.f};
            f32x4 a1 = {0.f, 0.f, 0.f, 0.f};
            a0 = __builtin_amdgcn_mfma_f32_16x16x32_bf16(axf, xf, a0, 0, 0, 0);
            #pragma unroll
            for (int c = 0; c < 4; ++c) {
                int k = w * 256 + c * 32 + khi;
                int byte = (bcol * 2048 + k * 2) ^ ((bcol & 7) << 4);
                bf16x8 af = *(const bf16x8*)((const char*)weff + byte);
                a0 = __builtin_amdgcn_mfma_f32_16x16x32_bf16(af, bfrag[c], a0, 0, 0, 0);
            }
            #pragma unroll
            for (int c = 4; c < 8; ++c) {
                int k = w * 256 + c * 32 + khi;
                int byte = (bcol * 2048 + k * 2) ^ ((bcol & 7) << 4);
                bf16x8 af = *(const bf16x8*)((const char*)weff + byte);
                a1 = __builtin_amdgcn_mfma_f32_16x16x32_bf16(af, bfrag[c], a1, 0, 0, 0);
            }
            acc = a0 + a1;
        }

        *(f32x4*)&red[w][0][lane][0] = acc;
        __syncthreads();

        if (t < T_) {
            // D mapping: col = lane&15 (=batch col), row = (lane>>4)*4 + reg (=n-local)
            int src = ((nl >> 2) << 4) | b_loc;
            int reg = nl & 3;
            float r = red[0][0][src][reg] + red[1][0][src][reg]
                    + red[2][0][src][reg] + red[3][0][src][reg];
            ahv = 0.9f * ahv + DT * (r + bahv);
            float th = tanhf(ahv);
            float h  = th > 0.f ? th : 0.f;
            unsigned hb = f2bf(h);
            unsigned nb = __shfl_down(hb, 1);
            if ((nl & 1) == 0 && b_loc < BPG) {
                unsigned tagw = (unsigned)(((t + 1) >> 1) & 1) << 31;
                unsigned w32 = hb | (nb << 16) | tagw;
                int eidx = ((g * 2 + (slot ^ 1)) * BPG + b_loc) * NREC + n_g;
                __hip_atomic_store((unsigned*)hbuf + (eidx >> 1), w32, __ATOMIC_RELAXED, SCOPE);
            }
            // no ack, no flag: each word self-announces via its tag
        }

        // ---- y for output step t-1 (off the critical inter-WG chain) ----
        if (t >= 1) {
            f32x4 accy = {0.f, 0.f, 0.f, 0.f};
            #pragma unroll
            for (int c = 0; c < 8; ++c) {
                int k = w * 256 + c * 32 + khi;
                bf16x8 af = *(const bf16x8*)((const char*)wyhs + k * 2);
                accy = __builtin_amdgcn_mfma_f32_16x16x32_bf16(af, bfrag[c], accy, 0, 0, 0);
            }
            *(f32x4*)&red[w][1][lane][0] = accy;
            __syncthreads();
            if (tid < BPG) {
                float yv = red[0][1][tid][0] + red[1][1][tid][0]
                         + red[2][1][tid][0] + red[3][1][tid][0] + byv;
                __builtin_nontemporal_store(yv, &y[((size_t)(g * BPG + tid) * T_ + (t - 1)) * NOUT + m]);
            }
        } else {
            // t==0 has no y-phase barrier; order red[][0] reads before t=1 writes.
            __syncthreads();
        }
    }
}

extern "C" void kernel_launch(void* const* d_in, const int* in_sizes, int n_in,
                              void* d_out, int out_size, void* d_ws, size_t ws_size,
                              hipStream_t stream) {
    const float* x    = (const float*)d_in[0];
    const float* Wahx = (const float*)d_in[1];
    const float* Wahh = (const float*)d_in[2];
    const float* Wyh  = (const float*)d_in[3];
    const float* bah  = (const float*)d_in[4];
    const float* by   = (const float*)d_in[5];
    const float* ah0  = (const float*)d_in[6];
    const float* mask = (const float*)d_in[7];
    float* y = (float*)d_out;
    char* ws = (char*)d_ws;
    unsigned short* xb   = (unsigned short*)(ws + XB_OFF);
    unsigned short* hbuf = (unsigned short*)(ws + HBUF_OFF);

    (void)in_sizes; (void)n_in; (void)out_size; (void)ws_size;

    // poison hbuf: all tag bits = 1, so phase-0 consumers (t=0,1) cannot
    // false-accept before the first writes land.
    hipMemsetAsync(hbuf, 0xFF, HBUF_BYTES, stream);
    cast_x_kernel<<<dim3(2048), dim3(256), 0, stream>>>(x, xb, (B_ * T_ * NIN) / 4);
    rnn_main<<<dim3(GROUPS * MEMBERS), dim3(256), 0, stream>>>(
        Wahx, Wahh, Wyh, bah, by, ah0, mask, xb, hbuf, y);
}

// Round 11
// 3174.217 us; speedup vs baseline: 2.3724x; 2.3724x over previous
//
#include <hip/hip_runtime.h>
#include <hip/hip_bf16.h>
#include <stdint.h>

// CTRNN: B=64, T=1000, N_IN=128, N_REC=1024, N_OUT=64
// Persistent-group design, round 13 (R4 + isolated single-barrier/y-defer):
//   grid = 256 WGs x 256 threads. group g = bid&3 (4 groups x 16 batches),
//   member m = bid>>2 (64 members, each owns 16 neurons and output o=m).
//   Base = R4 (3175us champion). ONE isolated change (the untested half of
//   R11; its spec-round-0 half caused that round's FETCH-triple regression):
//   SINGLE BARRIER PER STEP via parity double-buffering.
//     red0[t&1]: rec partials; red1[t&1]: y partials.
//     Order per iter: poll -> rec-GEMM -> write red0[slot] -> BARRIER ->
//     reduce+epilogue+h-store -> y-GEMM(write red1[slot]) ->
//     y-finalize step t-2 from red1[slot^1] -> loop.
//   Safety (intra-WG): a parity buffer read at t (after bar(t)) is
//   rewritten earliest at iter t+2, and the writer passed bar(t+1) which
//   the reader reaches only after finishing its t-reads. y-finalize reads
//   red1[slot^1] written at t-1 (post-bar(t-1)), ordered by bar(t); next
//   rewrite is at t+1 post-bar(t+1). One barrier suffices; t==0 extra
//   barrier also falls out. Removing bar2 additionally lets waves issue
//   next-step poll loads unsynchronized (earlier).
//   Exchange protocol (bit-identical to R4): tag in bit31 of each packed
//   32b h word (h=retanh>=0, sign free). Producer tags ((t+1)>>1)&1, just
//   stores (agent-relaxed). Consumer: per-chunk retry with per-lane pending
//   mask + s_sleep backoff. Period-4 slot/phase disambiguation; accepted
//   snapshot final; hbuf pre-poisoned 0xFF protects t=0/1.

#define B_    64
#define T_    1000
#define NIN   128
#define NREC  1024
#define NOUT  64
#define GROUPS  4
#define MEMBERS 64
#define BPG   16   // batches per group
#define NSL   16   // n-slice per member

#define DT    0.1f

typedef short  bf16x8 __attribute__((ext_vector_type(8)));
typedef float  f32x4  __attribute__((ext_vector_type(4)));

#define SCOPE __HIP_MEMORY_SCOPE_AGENT

// ws layout
#define XB_OFF     0
#define XB_BYTES   (B_ * T_ * NIN * 2)                      // 16,384,000 (16B aligned)
#define HBUF_OFF   (XB_OFF + XB_BYTES)
#define HBUF_BYTES (GROUPS * 2 * BPG * NREC * 2)            // 262,144

#define TAGMASK 0x8000000080000000ull

union U16B { unsigned long long q[2]; bf16x8 s; };

__device__ __forceinline__ unsigned short f2bf(float f) {
    unsigned u = __float_as_uint(f);
    unsigned r = u + 0x7fffu + ((u >> 16) & 1u);
    return (unsigned short)(r >> 16);
}
__device__ __forceinline__ unsigned pack2(float lo, float hi) {
    return (unsigned)f2bf(lo) | ((unsigned)f2bf(hi) << 16);
}

__global__ void cast_x_kernel(const float* __restrict__ x, unsigned short* __restrict__ xb, int n4) {
    int i = blockIdx.x * blockDim.x + threadIdx.x;
    int stride = gridDim.x * blockDim.x;
    for (; i < n4; i += stride) {
        float4 v = ((const float4*)x)[i];
        unsigned lo = pack2(v.x, v.y);
        unsigned hi = pack2(v.z, v.w);
        ((uint2*)xb)[i] = make_uint2(lo, hi);
    }
}

__global__ __launch_bounds__(256, 1)
void rnn_main(const float* __restrict__ Wahx, const float* __restrict__ Wahh,
              const float* __restrict__ Wyh,  const float* __restrict__ bah,
              const float* __restrict__ by,   const float* __restrict__ ah0,
              const float* __restrict__ mask,
              const unsigned short* __restrict__ xb,
              unsigned short* __restrict__ hbuf,
              float* __restrict__ y)
{
    __shared__ unsigned short weff[NSL * NREC];   // 32 KB, swizzled rows
    __shared__ unsigned short wahxs[NSL * NIN];   // 4 KB, swizzled rows
    __shared__ unsigned short wyhs[NREC];         // 2 KB, single row o=m
    __shared__ float red0[2][4][64][4];           // 8 KB: [par][wave][lane][reg] rec
    __shared__ float red1[2][4][64][4];           // 8 KB: [par][wave][lane][reg] y

    const int tid  = threadIdx.x;
    const int w    = tid >> 6;        // wave 0..3 (K-range w*256..)
    const int lane = tid & 63;
    const int bid  = blockIdx.x;
    const int g    = bid & 3;         // group
    const int m    = bid >> 2;        // member 0..63

    // ---- init: build LDS slabs ----
    for (int cc = 0; cc < 8; ++cc) {
        int cid = cc * 256 + tid;           // 2048 chunks of 8
        int rl = cid >> 7;                  // local row 0..15
        int k  = (cid & 127) * 8;
        const float* wr = Wahh + (m * NSL + rl) * NREC + k;
        const float* mr = mask + (m * NSL + rl) * NREC + k;
        float4 a0 = *(const float4*)wr;     float4 a1 = *(const float4*)(wr + 4);
        float4 m0 = *(const float4*)mr;     float4 m1 = *(const float4*)(mr + 4);
        uint4 pk;
        pk.x = pack2(fabsf(a0.x) * m0.x, fabsf(a0.y) * m0.y);
        pk.y = pack2(fabsf(a0.z) * m0.z, fabsf(a0.w) * m0.w);
        pk.z = pack2(fabsf(a1.x) * m1.x, fabsf(a1.y) * m1.y);
        pk.w = pack2(fabsf(a1.z) * m1.z, fabsf(a1.w) * m1.w);
        int byte = (rl * 2048 + k * 2) ^ ((rl & 7) << 4);
        *(uint4*)((char*)weff + byte) = pk;
    }
    {
        int rl = tid >> 4;
        int k  = (tid & 15) * 8;
        const float* wr = Wahx + (m * NSL + rl) * NIN + k;
        float4 a0 = *(const float4*)wr;  float4 a1 = *(const float4*)(wr + 4);
        uint4 pk;
        pk.x = pack2(a0.x, a0.y); pk.y = pack2(a0.z, a0.w);
        pk.z = pack2(a1.x, a1.y); pk.w = pack2(a1.z, a1.w);
        int byte = (rl * 256 + k * 2) ^ ((rl & 7) << 4);
        *(uint4*)((char*)wahxs + byte) = pk;
    }
    if (tid < 128) {
        int k = tid * 8;
        const float* wr = Wyh + m * NREC + k;
        float4 a0 = *(const float4*)wr;  float4 a1 = *(const float4*)(wr + 4);
        uint4 pk;
        pk.x = pack2(a0.x, a0.y); pk.y = pack2(a0.z, a0.w);
        pk.z = pack2(a1.x, a1.y); pk.w = pack2(a1.z, a1.w);
        *(uint4*)((char*)wyhs + k * 2) = pk;
    }

    // per-thread state: (b_loc, nl)
    const int b_loc = tid >> 4;
    const int nl    = tid & 15;
    const int n_g   = m * NSL + nl;
    float ahv  = ah0[n_g];
    float bahv = bah[n_g];
    float byv  = by[m];

    // h(0) = retanh(ah0) -> hbuf slot 0, tag 0 (natural sign bits)
    {
        float th = tanhf(ahv);
        float h0 = th > 0.f ? th : 0.f;
        unsigned hb = f2bf(h0);
        unsigned nb = __shfl_down(hb, 1);
        if ((nl & 1) == 0) {
            unsigned w32 = hb | (nb << 16);
            int eidx = ((g * 2 + 0) * BPG + b_loc) * NREC + n_g;
            __hip_atomic_store((unsigned*)hbuf + (eidx >> 1), w32, __ATOMIC_RELAXED, SCOPE);
        }
    }
    __syncthreads();   // LDS slabs ready before use

    const int bcol = lane & 15;          // batch col for MFMA, also A row
    const int khi  = (lane >> 4) * 8;    // per-lane k offset within 32-chunk

    for (int t = 0; t <= T_; ++t) {
        // ---- prefetch x fragment (independent of h(t)) ----
        bf16x8 xf, axf;
        if (t < T_) {
            int i = w * 32 + khi;
            xf = *(const bf16x8*)(xb + ((size_t)(g * BPG + bcol) * T_ + t) * NIN + i);
            int byte = (bcol * 256 + i * 2) ^ ((bcol & 7) << 4);
            axf = *(const bf16x8*)((const char*)wahxs + byte);
        }

        // ---- poll-load h(t): per-chunk retry, tags self-certify (R4 verbatim) ----
        const int slot = t & 1;
        const unsigned long long want = ((t >> 1) & 1) ? TAGMASK : 0ull;
        const unsigned long long* hq =
            (const unsigned long long*)(hbuf + ((g * 2 + slot) * BPG + bcol) * NREC);

        U16B u[8];
        unsigned pend = 0xFFu;           // per-lane pending chunk mask
        for (;;) {
            #pragma unroll
            for (int c = 0; c < 8; ++c) {
                if (pend & (1u << c)) {
                    int k = w * 256 + c * 32 + khi;
                    u[c].q[0] = __hip_atomic_load(hq + (k >> 2),     __ATOMIC_RELAXED, SCOPE);
                    u[c].q[1] = __hip_atomic_load(hq + (k >> 2) + 1, __ATOMIC_RELAXED, SCOPE);
                }
            }
            unsigned np = 0u;
            #pragma unroll
            for (int c = 0; c < 8; ++c) {
                if (pend & (1u << c)) {
                    unsigned long long d = ((u[c].q[0] ^ want) | (u[c].q[1] ^ want)) & TAGMASK;
                    np |= d ? (1u << c) : 0u;
                }
            }
            pend = np;
            if (!__any(pend != 0u)) break;
            __builtin_amdgcn_s_sleep(1);   // ~64cy backoff: don't hammer the LLC
        }
        bf16x8 bfrag[8];
        #pragma unroll
        for (int c = 0; c < 8; ++c) {
            u[c].q[0] &= ~TAGMASK;      // clear tags (real sign bits are 0)
            u[c].q[1] &= ~TAGMASK;
            bfrag[c] = u[c].s;
        }

        f32x4 acc = {0.f, 0.f, 0.f, 0.f};
        if (t < T_) {
            // two independent accumulators halve the serial MFMA dep chain
            f32x4 a0 = {0.f, 0.f, 0.f, 0.f};
            f32x4 a1 = {0.f, 0.f, 0.f, 0.f};
            a0 = __builtin_amdgcn_mfma_f32_16x16x32_bf16(axf, xf, a0, 0, 0, 0);
            #pragma unroll
            for (int c = 0; c < 4; ++c) {
                int k = w * 256 + c * 32 + khi;
                int byte = (bcol * 2048 + k * 2) ^ ((bcol & 7) << 4);
                bf16x8 af = *(const bf16x8*)((const char*)weff + byte);
                a0 = __builtin_amdgcn_mfma_f32_16x16x32_bf16(af, bfrag[c], a0, 0, 0, 0);
            }
            #pragma unroll
            for (int c = 4; c < 8; ++c) {
                int k = w * 256 + c * 32 + khi;
                int byte = (bcol * 2048 + k * 2) ^ ((bcol & 7) << 4);
                bf16x8 af = *(const bf16x8*)((const char*)weff + byte);
                a1 = __builtin_amdgcn_mfma_f32_16x16x32_bf16(af, bfrag[c], a1, 0, 0, 0);
            }
            acc = a0 + a1;
        }

        *(f32x4*)&red0[slot][w][lane][0] = acc;
        __syncthreads();                 // the ONLY barrier per step

        if (t < T_) {
            // D mapping: col = lane&15 (=batch), row = (lane>>4)*4 + reg (=n-local)
            int src = ((nl >> 2) << 4) | b_loc;
            int reg = nl & 3;
            float r = red0[slot][0][src][reg] + red0[slot][1][src][reg]
                    + red0[slot][2][src][reg] + red0[slot][3][src][reg];
            ahv = 0.9f * ahv + DT * (r + bahv);
            float th = tanhf(ahv);
            float h  = th > 0.f ? th : 0.f;
            unsigned hb = f2bf(h);
            unsigned nb = __shfl_down(hb, 1);
            if ((nl & 1) == 0) {
                unsigned tagw = (unsigned)(((t + 1) >> 1) & 1) << 31;
                unsigned w32 = hb | (nb << 16) | tagw;
                int eidx = ((g * 2 + (slot ^ 1)) * BPG + b_loc) * NREC + n_g;
                __hip_atomic_store((unsigned*)hbuf + (eidx >> 1), w32, __ATOMIC_RELAXED, SCOPE);
            }
            // no ack, no flag: each word self-announces via its tag
        }

        // ---- y-GEMM for output step t-1 (same bfrag; after the h store;
        //      no second barrier — result lands in red1[slot]) ----
        if (t >= 1) {
            f32x4 y0 = {0.f, 0.f, 0.f, 0.f};
            f32x4 y1 = {0.f, 0.f, 0.f, 0.f};
            #pragma unroll
            for (int c = 0; c < 4; ++c) {
                int k = w * 256 + c * 32 + khi;
                bf16x8 af = *(const bf16x8*)((const char*)wyhs + k * 2);
                y0 = __builtin_amdgcn_mfma_f32_16x16x32_bf16(af, bfrag[c], y0, 0, 0, 0);
            }
            #pragma unroll
            for (int c = 4; c < 8; ++c) {
                int k = w * 256 + c * 32 + khi;
                bf16x8 af = *(const bf16x8*)((const char*)wyhs + k * 2);
                y1 = __builtin_amdgcn_mfma_f32_16x16x32_bf16(af, bfrag[c], y1, 0, 0, 0);
            }
            *(f32x4*)&red1[slot][w][lane][0] = y0 + y1;
        }

        // ---- y-finalize for output step t-2 (red1[slot^1], written at t-1
        //      post-bar(t-1); bar(t) ordered those writes; next rewrite is
        //      at t+1 post-bar(t+1) -> safe with one barrier) ----
        if (t >= 2 && tid < BPG) {
            float yv = red1[slot ^ 1][0][tid][0] + red1[slot ^ 1][1][tid][0]
                     + red1[slot ^ 1][2][tid][0] + red1[slot ^ 1][3][tid][0] + byv;
            __builtin_nontemporal_store(yv, &y[((size_t)(g * BPG + tid) * T_ + (t - 2)) * NOUT + m]);
        }
    }

    // ---- drain: y for output step T-1 (red1[T_&1] written at t=T_) ----
    __syncthreads();
    if (tid < BPG) {
        const int p = T_ & 1;
        float yv = red1[p][0][tid][0] + red1[p][1][tid][0]
                 + red1[p][2][tid][0] + red1[p][3][tid][0] + byv;
        __builtin_nontemporal_store(yv, &y[((size_t)(g * BPG + tid) * T_ + (T_ - 1)) * NOUT + m]);
    }
}

extern "C" void kernel_launch(void* const* d_in, const int* in_sizes, int n_in,
                              void* d_out, int out_size, void* d_ws, size_t ws_size,
                              hipStream_t stream) {
    const float* x    = (const float*)d_in[0];
    const float* Wahx = (const float*)d_in[1];
    const float* Wahh = (const float*)d_in[2];
    const float* Wyh  = (const float*)d_in[3];
    const float* bah  = (const float*)d_in[4];
    const float* by   = (const float*)d_in[5];
    const float* ah0  = (const float*)d_in[6];
    const float* mask = (const float*)d_in[7];
    float* y = (float*)d_out;
    char* ws = (char*)d_ws;
    unsigned short* xb   = (unsigned short*)(ws + XB_OFF);
    unsigned short* hbuf = (unsigned short*)(ws + HBUF_OFF);

    (void)in_sizes; (void)n_in; (void)out_size; (void)ws_size;

    // poison hbuf: all tag bits = 1, so phase-0 consumers (t=0,1) cannot
    // false-accept before the first writes land.
    hipMemsetAsync(hbuf, 0xFF, HBUF_BYTES, stream);
    cast_x_kernel<<<dim3(2048), dim3(256), 0, stream>>>(x, xb, (B_ * T_ * NIN) / 4);
    rnn_main<<<dim3(GROUPS * MEMBERS), dim3(256), 0, stream>>>(
        Wahx, Wahh, Wyh, bah, by, ah0, mask, xb, hbuf, y);
}